// Round 4
// baseline (289.535 us; speedup 1.0000x reference)
//
#include <hip/hip_runtime.h>
#include <math.h>

// EWRLS level filter. Recurrence collapses to a pure decay scan:
//   S_t = lam*S_{t-1} + x_t,  Q_t = lam*Q_{t-1} + 1,  y_t = S_t / Q_t
//
// R6 -> R7: R6 fixed traffic (FETCH ~= one x pass) but ran latency-bound:
// VALUBusy 5%, Occupancy 17% (grid = 512 blocks = 2/CU was the cap).
//  1. kNCH 16->32 (kL=32): 2048 chunks -> 1024 blocks = 4/CU, 16 waves/CU.
//     All blocks still fully co-resident (VGPR ~40) -> same deadlock-free
//     ticket argument, but 2x resident waves to hide HBM/L2 latency.
//  2. Lookback polls batched: issue the 4 packed carry words of a
//     predecessor independently, test their flags together (1 dependent
//     L2 round trip per predecessor instead of 4 serial spins).
// Carry publish stays fence-free: (flag<<32 | float_bits) in one 64-bit
// relaxed agent-scope atom.

namespace {
constexpr int kB = 64;
constexpr int kT = 1024;
constexpr int kC = 512;
constexpr int kNCH = 32;              // chunks along T
constexpr int kL = kT / kNCH;         // 32 steps per chunk
constexpr int kCV = kC / 4;           // 128 float4 lanes per row
constexpr int kChunks = kB * kNCH;    // 2048
constexpr int kBlocks = kChunks / 2;  // 1024 (2 chunks per 256-thr block)
// ws layout (bytes):
//   [0]      uint ticket counter
//   [1024]   u64 carry[kChunks][kCV][4]   (8 MiB) packed (flag<<32 | bits)
constexpr size_t kCarryOffB = 1024;
constexpr size_t kCarryU64 = (size_t)kChunks * kCV * 4;  // 1048576
}

typedef float vfloat4 __attribute__((ext_vector_type(4)));

__device__ __forceinline__ void load_lam(const float* __restrict__ zl, int c0,
                                         float lam[4]) {
  vfloat4 z = *reinterpret_cast<const vfloat4*>(zl + c0);
#pragma unroll
  for (int k = 0; k < 4; ++k) {
    float s = 1.0f / (1.0f + expf(-z[k]));
    lam[k] = fminf(fmaxf(s, 1e-4f), 1.0f - 1e-4f);
  }
}

__device__ __forceinline__ unsigned long long ld_carry(
    const unsigned long long* __restrict__ p) {
  return __hip_atomic_load(p, __ATOMIC_RELAXED, __HIP_MEMORY_SCOPE_AGENT);
}

// Load one predecessor's 4 packed words; all 4 issued independently, flags
// tested together; retry only while any flag is missing.
__device__ __forceinline__ void poll4(const unsigned long long* __restrict__ p,
                                      float v[4]) {
  unsigned long long u0 = ld_carry(p + 0);
  unsigned long long u1 = ld_carry(p + 1);
  unsigned long long u2 = ld_carry(p + 2);
  unsigned long long u3 = ld_carry(p + 3);
  while (!((u0 >> 32) & (u1 >> 32) & (u2 >> 32) & (u3 >> 32))) {
    __builtin_amdgcn_s_sleep(1);
    u0 = ld_carry(p + 0);
    u1 = ld_carry(p + 1);
    u2 = ld_carry(p + 2);
    u3 = ld_carry(p + 3);
  }
  union { unsigned u32; float f; } c;
  c.u32 = (unsigned)u0; v[0] = c.f;
  c.u32 = (unsigned)u1; v[1] = c.f;
  c.u32 = (unsigned)u2; v[2] = c.f;
  c.u32 = (unsigned)u3; v[3] = c.f;
}

// Zero ticket + all packed-carry words (workspace is poisoned between
// iterations; poison could have flag bits set, so this must run).
extern "C" __global__ __launch_bounds__(256) void ewrls_init(
    unsigned long long* __restrict__ cw, unsigned* __restrict__ tk) {
  size_t i = (size_t)blockIdx.x * 256 + threadIdx.x;
  if (i < kCarryU64) cw[i] = 0ull;
  if (i == 0) *tk = 0u;
}

// Single-pass chunked scan, decoupled lookback, fence-free.
// chunk id c = j*kB + b; block ticket T owns chunks {2T, 2T+1} (same j).
// Predecessors of (j,b) are (i<j,b): smaller c -> smaller ticket -> owner
// resident (grid of 1024 = 4 blocks/CU x 256 CU, fully co-resident) and
// its publish path is wait-free => no deadlock.
extern "C" __global__ __launch_bounds__(256) void ewrls_fused(
    const float* __restrict__ x, const float* __restrict__ zl,
    unsigned* __restrict__ ws, float* __restrict__ y) {
  __shared__ unsigned sh_t;
  if (threadIdx.x == 0)
    sh_t = __hip_atomic_fetch_add(ws, 1u, __ATOMIC_RELAXED,
                                  __HIP_MEMORY_SCOPE_AGENT);
  __syncthreads();
  const unsigned T = sh_t;
  const int c = (int)(2u * T) + (int)(threadIdx.x >> 7);
  const int j = c >> 6;                // c / kB
  const int b = c & 63;                // c % kB
  const int cv = threadIdx.x & 127;

  unsigned long long* __restrict__ carry =
      reinterpret_cast<unsigned long long*>(
          reinterpret_cast<char*>(ws) + kCarryOffB);

  float lam[4];
  load_lam(zl, cv * 4, lam);

  // Phase A: local decayed aggregate. CACHING loads (want x in L2/L3 for
  // phase B's re-read).
  const size_t base = ((size_t)b * kT + (size_t)j * kL) * kCV + cv;
  const vfloat4* xp = reinterpret_cast<const vfloat4*>(x) + base;
  float a0 = 0.f, a1 = 0.f, a2 = 0.f, a3 = 0.f;
#pragma unroll 8
  for (int t = 0; t < kL; ++t) {
    vfloat4 v = xp[(size_t)t * kCV];
    a0 = fmaf(lam[0], a0, v.x);
    a1 = fmaf(lam[1], a1, v.y);
    a2 = fmaf(lam[2], a2, v.z);
    a3 = fmaf(lam[3], a3, v.w);
  }

  // Publish: packed (1<<32 | bits) relaxed agent atomics. Flag travels
  // with data in one atom -> no fences anywhere.
  {
    unsigned long long* cp = carry + (((size_t)c * kCV + cv) << 2);
    union { float f; unsigned u; } q;
    q.f = a0;
    __hip_atomic_store(cp + 0, (1ull << 32) | q.u, __ATOMIC_RELAXED,
                       __HIP_MEMORY_SCOPE_AGENT);
    q.f = a1;
    __hip_atomic_store(cp + 1, (1ull << 32) | q.u, __ATOMIC_RELAXED,
                       __HIP_MEMORY_SCOPE_AGENT);
    q.f = a2;
    __hip_atomic_store(cp + 2, (1ull << 32) | q.u, __ATOMIC_RELAXED,
                       __HIP_MEMORY_SCOPE_AGENT);
    q.f = a3;
    __hip_atomic_store(cp + 3, (1ull << 32) | q.u, __ATOMIC_RELAXED,
                       __HIP_MEMORY_SCOPE_AGENT);
  }

  // lam^kL (kL = 32 -> 5 squarings).
  float lamL[4];
#pragma unroll
  for (int k = 0; k < 4; ++k) {
    float p = lam[k];
#pragma unroll
    for (int q = 0; q < 5; ++q) p = p * p;
    lamL[k] = p;
  }

  // Lookback: fold predecessor aggregates (ascending i = verified fold).
  float S0 = 0.f, S1 = 0.f, S2 = 0.f, S3 = 0.f;
  float p0 = 1.f, p1 = 1.f, p2 = 1.f, p3 = 1.f;
  for (int i = 0; i < j; ++i) {
    const unsigned long long* cp =
        carry + ((((size_t)i * kB + b) * kCV + cv) << 2);
    float v[4];
    poll4(cp, v);
    S0 = fmaf(lamL[0], S0, v[0]);
    S1 = fmaf(lamL[1], S1, v[1]);
    S2 = fmaf(lamL[2], S2, v[2]);
    S3 = fmaf(lamL[3], S3, v[3]);
    p0 *= lamL[0];
    p1 *= lamL[1];
    p2 *= lamL[2];
    p3 *= lamL[3];
  }

  // Seed Q closed-form: Q_{j*kL-1} = (1 - lam^(j*kL)) / (1 - lam).
  float Q0 = (1.0f - p0) * __builtin_amdgcn_rcpf(1.0f - lam[0]);
  float Q1 = (1.0f - p1) * __builtin_amdgcn_rcpf(1.0f - lam[1]);
  float Q2 = (1.0f - p2) * __builtin_amdgcn_rcpf(1.0f - lam[2]);
  float Q3 = (1.0f - p3) * __builtin_amdgcn_rcpf(1.0f - lam[3]);

  // Phase B: re-read x (nt: evict-first, it's L2/L3-hot), scan, nt store.
  vfloat4* yp = reinterpret_cast<vfloat4*>(y) + base;
#pragma unroll 8
  for (int t = 0; t < kL; ++t) {
    vfloat4 v = __builtin_nontemporal_load(&xp[(size_t)t * kCV]);
    S0 = fmaf(lam[0], S0, v.x);
    S1 = fmaf(lam[1], S1, v.y);
    S2 = fmaf(lam[2], S2, v.z);
    S3 = fmaf(lam[3], S3, v.w);
    Q0 = fmaf(lam[0], Q0, 1.0f);
    Q1 = fmaf(lam[1], Q1, 1.0f);
    Q2 = fmaf(lam[2], Q2, 1.0f);
    Q3 = fmaf(lam[3], Q3, 1.0f);
    vfloat4 o;
    o.x = S0 * __builtin_amdgcn_rcpf(Q0);
    o.y = S1 * __builtin_amdgcn_rcpf(Q1);
    o.z = S2 * __builtin_amdgcn_rcpf(Q2);
    o.w = S3 * __builtin_amdgcn_rcpf(Q3);
    __builtin_nontemporal_store(o, &yp[(size_t)t * kCV]);
  }
}

// Fallback if workspace is too small: fully sequential over T per (b, 4ch).
extern "C" __global__ __launch_bounds__(256) void ewrls_serial(
    const float* __restrict__ x, const float* __restrict__ zl,
    float* __restrict__ y) {
  int idx = blockIdx.x * 256 + threadIdx.x;   // [0, kB*kCV)
  int cv = idx % kCV;
  int b = idx / kCV;
  float lam[4];
  load_lam(zl, cv * 4, lam);
  float S[4] = {0.f, 0.f, 0.f, 0.f};
  float Q[4] = {0.f, 0.f, 0.f, 0.f};
  const size_t base = (size_t)b * kT * kCV + cv;
  const vfloat4* xp = reinterpret_cast<const vfloat4*>(x) + base;
  vfloat4* yp = reinterpret_cast<vfloat4*>(y) + base;
#pragma unroll 4
  for (int t = 0; t < kT; ++t) {
    vfloat4 v = xp[(size_t)t * kCV];
    S[0] = fmaf(lam[0], S[0], v.x);
    S[1] = fmaf(lam[1], S[1], v.y);
    S[2] = fmaf(lam[2], S[2], v.z);
    S[3] = fmaf(lam[3], S[3], v.w);
    Q[0] = fmaf(lam[0], Q[0], 1.0f);
    Q[1] = fmaf(lam[1], Q[1], 1.0f);
    Q[2] = fmaf(lam[2], Q[2], 1.0f);
    Q[3] = fmaf(lam[3], Q[3], 1.0f);
    vfloat4 o;
    o.x = S[0] * __builtin_amdgcn_rcpf(Q[0]);
    o.y = S[1] * __builtin_amdgcn_rcpf(Q[1]);
    o.z = S[2] * __builtin_amdgcn_rcpf(Q[2]);
    o.w = S[3] * __builtin_amdgcn_rcpf(Q[3]);
    yp[(size_t)t * kCV] = o;
  }
}

extern "C" void kernel_launch(void* const* d_in, const int* in_sizes, int n_in,
                              void* d_out, int out_size, void* d_ws,
                              size_t ws_size, hipStream_t stream) {
  const float* x = (const float*)d_in[0];
  const float* zl = (const float*)d_in[1];
  float* y = (float*)d_out;

  const size_t need = kCarryOffB + kCarryU64 * 8;  // ~8.001 MiB
  if (ws_size >= need) {
    unsigned* ws = (unsigned*)d_ws;
    unsigned long long* cw = reinterpret_cast<unsigned long long*>(
        reinterpret_cast<char*>(d_ws) + kCarryOffB);
    ewrls_init<<<(int)((kCarryU64 + 255) / 256), 256, 0, stream>>>(cw, ws);
    ewrls_fused<<<kBlocks, 256, 0, stream>>>(x, zl, ws, y);
  } else {
    const int n = kB * kCV;                 // 8192 -> 32 blocks
    ewrls_serial<<<n / 256, 256, 0, stream>>>(x, zl, y);
  }
}

// Round 5
// 254.347 us; speedup vs baseline: 1.1383x; 1.1383x over previous
//
#include <hip/hip_runtime.h>
#include <math.h>

// EWRLS level filter. Recurrence collapses to a pure decay scan:
//   S_t = lam*S_{t-1} + x_t,  Q_t = lam*Q_{t-1} + 1,  y_t = S_t / Q_t
//
// R7 -> R8: R7 (32 chunks/T) regressed: lookback depth 31 quadrupled the
// O(chunks^2) carry-fold traffic; extra occupancy was spent spinning
// (VALUBusy stayed 5%). R8 decouples chunk-parallelism from wave-
// parallelism with an intra-block hierarchy:
//   block = 512 thr = one (b, 128-step window) = 4 sub-chunks x 32 steps.
//   - 4 sub-chunks stream x in parallel (grid 512 blocks x 8 waves =
//     50% occupancy, 2x R6)
//   - sub-aggregates combined in LDS (no global sync)
//   - global lookback over BLOCK aggregates only: depth <= 7 (half R6),
//     carries 2 MiB, fold traffic ~7 MB (R6 33 MB, R7 130 MB)
// Publish stays fence-free: (flag<<32 | float_bits) packed in one 64-bit
// relaxed agent-scope atom. Ticket per block; predecessors have strictly
// smaller tickets -> resident, wait-free publish -> deadlock-free.

namespace {
constexpr int kB = 64;
constexpr int kT = 1024;
constexpr int kC = 512;
constexpr int kTW = 8;                // T-windows (one block each per b)
constexpr int kWL = kT / kTW;         // 128 steps per window
constexpr int kSC = 4;                // sub-chunks per window
constexpr int kSL = kWL / kSC;        // 32 steps per sub-chunk
constexpr int kCV = kC / 4;           // 128 float4 lanes per row
constexpr int kChunks = kB * kTW;     // 512 == grid size
// ws layout (bytes):
//   [0]      uint ticket counter
//   [1024]   u64 carry[kChunks][kCV][4]   (2 MiB) packed (flag<<32 | bits)
constexpr size_t kCarryOffB = 1024;
constexpr size_t kCarryU64 = (size_t)kChunks * kCV * 4;  // 262144
}

typedef float vfloat4 __attribute__((ext_vector_type(4)));

__device__ __forceinline__ void load_lam(const float* __restrict__ zl, int c0,
                                         float lam[4]) {
  vfloat4 z = *reinterpret_cast<const vfloat4*>(zl + c0);
#pragma unroll
  for (int k = 0; k < 4; ++k) {
    float s = 1.0f / (1.0f + expf(-z[k]));
    lam[k] = fminf(fmaxf(s, 1e-4f), 1.0f - 1e-4f);
  }
}

__device__ __forceinline__ unsigned long long ld_carry(
    const unsigned long long* __restrict__ p) {
  return __hip_atomic_load(p, __ATOMIC_RELAXED, __HIP_MEMORY_SCOPE_AGENT);
}

// Load one predecessor's 4 packed words; issued independently, flags tested
// together; retry only while any flag is missing (1 round trip typical).
__device__ __forceinline__ void poll4(const unsigned long long* __restrict__ p,
                                      float v[4]) {
  unsigned long long u0 = ld_carry(p + 0);
  unsigned long long u1 = ld_carry(p + 1);
  unsigned long long u2 = ld_carry(p + 2);
  unsigned long long u3 = ld_carry(p + 3);
  while (!((u0 >> 32) & (u1 >> 32) & (u2 >> 32) & (u3 >> 32))) {
    __builtin_amdgcn_s_sleep(1);
    u0 = ld_carry(p + 0);
    u1 = ld_carry(p + 1);
    u2 = ld_carry(p + 2);
    u3 = ld_carry(p + 3);
  }
  union { unsigned u32; float f; } c;
  c.u32 = (unsigned)u0; v[0] = c.f;
  c.u32 = (unsigned)u1; v[1] = c.f;
  c.u32 = (unsigned)u2; v[2] = c.f;
  c.u32 = (unsigned)u3; v[3] = c.f;
}

// Zero ticket + packed-carry words (workspace is poisoned每 iteration and
// poison may have flag bits set, so this must run every call).
extern "C" __global__ __launch_bounds__(256) void ewrls_init(
    unsigned long long* __restrict__ cw, unsigned* __restrict__ tk) {
  size_t i = (size_t)blockIdx.x * 256 + threadIdx.x;
  if (i < kCarryU64) cw[i] = 0ull;
  if (i == 0) *tk = 0u;
}

// One block per (b, 128-step window). chunk id c = j*kB + b (j-major).
extern "C" __global__ __launch_bounds__(512) void ewrls_fused(
    const float* __restrict__ x, const float* __restrict__ zl,
    unsigned* __restrict__ ws, float* __restrict__ y) {
  __shared__ unsigned sh_t;
  __shared__ vfloat4 lds_agg[kSC][kCV];   // 8 KiB sub-chunk aggregates
  __shared__ vfloat4 lds_G[kCV];          // 2 KiB looked-back global prefix
  if (threadIdx.x == 0)
    sh_t = __hip_atomic_fetch_add(ws, 1u, __ATOMIC_RELAXED,
                                  __HIP_MEMORY_SCOPE_AGENT);
  __syncthreads();
  const int c = (int)sh_t;
  const int j = c >> 6;                 // window index  (c / kB)
  const int b = c & 63;                 // batch row     (c % kB)
  const int s = threadIdx.x >> 7;       // sub-chunk 0..3 (wave-uniform)
  const int cv = threadIdx.x & 127;

  unsigned long long* __restrict__ carry =
      reinterpret_cast<unsigned long long*>(
          reinterpret_cast<char*>(ws) + kCarryOffB);

  float lam[4];
  load_lam(zl, cv * 4, lam);

  // lam^kSL (kSL = 32 -> 5 squarings).
  float lam32[4];
#pragma unroll
  for (int k = 0; k < 4; ++k) {
    float p = lam[k];
#pragma unroll
    for (int q = 0; q < 5; ++q) p = p * p;
    lam32[k] = p;
  }

  // Phase A: local decayed aggregate of this sub-chunk. CACHING loads
  // (want x resident in L2/L3 for phase B's re-read).
  const size_t base =
      ((size_t)b * kT + (size_t)j * kWL + (size_t)s * kSL) * kCV + cv;
  const vfloat4* xp = reinterpret_cast<const vfloat4*>(x) + base;
  float a0 = 0.f, a1 = 0.f, a2 = 0.f, a3 = 0.f;
#pragma unroll 8
  for (int t = 0; t < kSL; ++t) {
    vfloat4 v = xp[(size_t)t * kCV];
    a0 = fmaf(lam[0], a0, v.x);
    a1 = fmaf(lam[1], a1, v.y);
    a2 = fmaf(lam[2], a2, v.z);
    a3 = fmaf(lam[3], a3, v.w);
  }
  {
    vfloat4 a = {a0, a1, a2, a3};
    lds_agg[s][cv] = a;
  }
  __syncthreads();

  // Local prefix L_s = fold of sub-aggregates i < s (ascending; s is
  // wave-uniform so no divergence).
  float S0 = 0.f, S1 = 0.f, S2 = 0.f, S3 = 0.f;
  for (int i = 0; i < s; ++i) {
    vfloat4 ai = lds_agg[i][cv];
    S0 = fmaf(lam32[0], S0, ai.x);
    S1 = fmaf(lam32[1], S1, ai.y);
    S2 = fmaf(lam32[2], S2, ai.z);
    S3 = fmaf(lam32[3], S3, ai.w);
  }

  // lam^kWL (128) for the global fold / Q seed.
  float l128[4];
#pragma unroll
  for (int k = 0; k < 4; ++k) {
    float p = lam32[k];
    p = p * p;
    l128[k] = p * p;
  }

  // Sub-group s==0 (2 waves): block aggregate -> publish -> lookback -> LDS.
  if (s == 0) {
    float A0 = 0.f, A1 = 0.f, A2 = 0.f, A3 = 0.f;
#pragma unroll
    for (int i = 0; i < kSC; ++i) {
      vfloat4 ai = lds_agg[i][cv];
      A0 = fmaf(lam32[0], A0, ai.x);
      A1 = fmaf(lam32[1], A1, ai.y);
      A2 = fmaf(lam32[2], A2, ai.z);
      A3 = fmaf(lam32[3], A3, ai.w);
    }
    // Publish packed (flag|bits): wait-free, before any poll.
    {
      unsigned long long* cp = carry + (((size_t)c * kCV + cv) << 2);
      union { float f; unsigned u; } q;
      q.f = A0;
      __hip_atomic_store(cp + 0, (1ull << 32) | q.u, __ATOMIC_RELAXED,
                         __HIP_MEMORY_SCOPE_AGENT);
      q.f = A1;
      __hip_atomic_store(cp + 1, (1ull << 32) | q.u, __ATOMIC_RELAXED,
                         __HIP_MEMORY_SCOPE_AGENT);
      q.f = A2;
      __hip_atomic_store(cp + 2, (1ull << 32) | q.u, __ATOMIC_RELAXED,
                         __HIP_MEMORY_SCOPE_AGENT);
      q.f = A3;
      __hip_atomic_store(cp + 3, (1ull << 32) | q.u, __ATOMIC_RELAXED,
                         __HIP_MEMORY_SCOPE_AGENT);
    }
    // Lookback over block predecessors (depth <= kTW-1 = 7, ascending).
    float G0 = 0.f, G1 = 0.f, G2 = 0.f, G3 = 0.f;
    for (int i = 0; i < j; ++i) {
      const unsigned long long* cp =
          carry + ((((size_t)i * kB + b) * kCV + cv) << 2);
      float v[4];
      poll4(cp, v);
      G0 = fmaf(l128[0], G0, v[0]);
      G1 = fmaf(l128[1], G1, v[1]);
      G2 = fmaf(l128[2], G2, v[2]);
      G3 = fmaf(l128[3], G3, v[3]);
    }
    vfloat4 g = {G0, G1, G2, G3};
    lds_G[cv] = g;
  }
  __syncthreads();

  // Seed: S = L_s + lam^(32s) * G ;  Q from closed form with
  // p = lam^(128j + 32s) = l128^j * lam32^s.
  float sc[4] = {1.f, 1.f, 1.f, 1.f};
  for (int i = 0; i < s; ++i) {
#pragma unroll
    for (int k = 0; k < 4; ++k) sc[k] *= lam32[k];
  }
  float pj[4] = {1.f, 1.f, 1.f, 1.f};
  for (int i = 0; i < j; ++i) {
#pragma unroll
    for (int k = 0; k < 4; ++k) pj[k] *= l128[k];
  }
  {
    vfloat4 g = lds_G[cv];
    S0 = fmaf(sc[0], g.x, S0);
    S1 = fmaf(sc[1], g.y, S1);
    S2 = fmaf(sc[2], g.z, S2);
    S3 = fmaf(sc[3], g.w, S3);
  }
  float Q0 = (1.0f - pj[0] * sc[0]) * __builtin_amdgcn_rcpf(1.0f - lam[0]);
  float Q1 = (1.0f - pj[1] * sc[1]) * __builtin_amdgcn_rcpf(1.0f - lam[1]);
  float Q2 = (1.0f - pj[2] * sc[2]) * __builtin_amdgcn_rcpf(1.0f - lam[2]);
  float Q3 = (1.0f - pj[3] * sc[3]) * __builtin_amdgcn_rcpf(1.0f - lam[3]);

  // Phase B: re-read x (nt: single-use now, L2/L3-hot), scan, nt store.
  vfloat4* yp = reinterpret_cast<vfloat4*>(y) + base;
#pragma unroll 8
  for (int t = 0; t < kSL; ++t) {
    vfloat4 v = __builtin_nontemporal_load(&xp[(size_t)t * kCV]);
    S0 = fmaf(lam[0], S0, v.x);
    S1 = fmaf(lam[1], S1, v.y);
    S2 = fmaf(lam[2], S2, v.z);
    S3 = fmaf(lam[3], S3, v.w);
    Q0 = fmaf(lam[0], Q0, 1.0f);
    Q1 = fmaf(lam[1], Q1, 1.0f);
    Q2 = fmaf(lam[2], Q2, 1.0f);
    Q3 = fmaf(lam[3], Q3, 1.0f);
    vfloat4 o;
    o.x = S0 * __builtin_amdgcn_rcpf(Q0);
    o.y = S1 * __builtin_amdgcn_rcpf(Q1);
    o.z = S2 * __builtin_amdgcn_rcpf(Q2);
    o.w = S3 * __builtin_amdgcn_rcpf(Q3);
    __builtin_nontemporal_store(o, &yp[(size_t)t * kCV]);
  }
}

// Fallback if workspace is too small: fully sequential over T per (b, 4ch).
extern "C" __global__ __launch_bounds__(256) void ewrls_serial(
    const float* __restrict__ x, const float* __restrict__ zl,
    float* __restrict__ y) {
  int idx = blockIdx.x * 256 + threadIdx.x;   // [0, kB*kCV)
  int cv = idx % kCV;
  int b = idx / kCV;
  float lam[4];
  load_lam(zl, cv * 4, lam);
  float S[4] = {0.f, 0.f, 0.f, 0.f};
  float Q[4] = {0.f, 0.f, 0.f, 0.f};
  const size_t base = (size_t)b * kT * kCV + cv;
  const vfloat4* xp = reinterpret_cast<const vfloat4*>(x) + base;
  vfloat4* yp = reinterpret_cast<vfloat4*>(y) + base;
#pragma unroll 4
  for (int t = 0; t < kT; ++t) {
    vfloat4 v = xp[(size_t)t * kCV];
    S[0] = fmaf(lam[0], S[0], v.x);
    S[1] = fmaf(lam[1], S[1], v.y);
    S[2] = fmaf(lam[2], S[2], v.z);
    S[3] = fmaf(lam[3], S[3], v.w);
    Q[0] = fmaf(lam[0], Q[0], 1.0f);
    Q[1] = fmaf(lam[1], Q[1], 1.0f);
    Q[2] = fmaf(lam[2], Q[2], 1.0f);
    Q[3] = fmaf(lam[3], Q[3], 1.0f);
    vfloat4 o;
    o.x = S[0] * __builtin_amdgcn_rcpf(Q[0]);
    o.y = S[1] * __builtin_amdgcn_rcpf(Q[1]);
    o.z = S[2] * __builtin_amdgcn_rcpf(Q[2]);
    o.w = S[3] * __builtin_amdgcn_rcpf(Q[3]);
    yp[(size_t)t * kCV] = o;
  }
}

extern "C" void kernel_launch(void* const* d_in, const int* in_sizes, int n_in,
                              void* d_out, int out_size, void* d_ws,
                              size_t ws_size, hipStream_t stream) {
  const float* x = (const float*)d_in[0];
  const float* zl = (const float*)d_in[1];
  float* y = (float*)d_out;

  const size_t need = kCarryOffB + kCarryU64 * 8;  // ~2.001 MiB
  if (ws_size >= need) {
    unsigned* ws = (unsigned*)d_ws;
    unsigned long long* cw = reinterpret_cast<unsigned long long*>(
        reinterpret_cast<char*>(d_ws) + kCarryOffB);
    ewrls_init<<<(int)((kCarryU64 + 255) / 256), 256, 0, stream>>>(cw, ws);
    ewrls_fused<<<kChunks, 512, 0, stream>>>(x, zl, ws, y);
  } else {
    const int n = kB * kCV;                 // 8192 -> 32 blocks
    ewrls_serial<<<n / 256, 256, 0, stream>>>(x, zl, y);
  }
}